// Round 7
// baseline (95.598 us; speedup 1.0000x reference)
//
#include <hip/hip_runtime.h>

typedef __attribute__((ext_vector_type(8))) short bf16x8;
typedef __attribute__((ext_vector_type(4))) float f32x4;
typedef unsigned short us;

#define NATOMS 65536
#define NIN 256
#define NHID 512
#define TM 64

__device__ __forceinline__ us f2b(float f) {
    union { float f; unsigned int u; } a; a.f = f;
    unsigned int r = a.u + 0x7FFFu + ((a.u >> 16) & 1u);
    return (us)(r >> 16);
}
__device__ __forceinline__ float b2f(us h) {
    union { unsigned int u; float f; } a; a.u = ((unsigned int)h) << 16;
    return a.f;
}
__device__ __forceinline__ float fast_tanh(float v) {
    float e = __expf(2.f * v);
    return 1.f - 2.f / (e + 1.f);
}

// Pack W1/W2 into MFMA-fragment order: chunk[(ntile*KS + kstep)*64 + lane] =
// W[n= ntile*16+(lane&15)][k= kstep*32+(lane>>4)*8 .. +8) as bf16x8.
// A wave's B-fragment load is then one coalesced 1 KB transaction.
__global__ void cvt_kernel(const float* __restrict__ W1, const float* __restrict__ W2,
                           const float* __restrict__ W3,
                           us* __restrict__ W1p, us* __restrict__ W2p,
                           us* __restrict__ W3b) {
    int i = blockIdx.x * blockDim.x + threadIdx.x;
    if (i < 65536) {               // W1: 4 species * 32 ntiles * 8 ksteps * 64 lanes
        int s = i >> 14, rem = i & 16383;
        int ntile = rem >> 9, r2 = rem & 511;
        int kstep = r2 >> 6, lane = r2 & 63;
        int n = ntile * 16 + (lane & 15);
        int k = kstep * 32 + ((lane >> 4) << 3);
        const float* src = W1 + ((size_t)(s * NHID + n) * NIN + k);
        us p[8];
#pragma unroll
        for (int j = 0; j < 8; ++j) p[j] = f2b(src[j]);
        *(uint4*)(W1p + (size_t)i * 8) = *(uint4*)p;
    }
    if (i < 131072) {              // W2: 4 * 32 * 16 * 64
        int s = i >> 15, rem = i & 32767;
        int ntile = rem >> 10, r2 = rem & 1023;
        int kstep = r2 >> 6, lane = r2 & 63;
        int n = ntile * 16 + (lane & 15);
        int k = kstep * 32 + ((lane >> 4) << 3);
        const float* src = W2 + ((size_t)(s * NHID + n) * NHID + k);
        us p[8];
#pragma unroll
        for (int j = 0; j < 8; ++j) p[j] = f2b(src[j]);
        *(uint4*)(W2p + (size_t)i * 8) = *(uint4*)p;
    }
    if (i < 2048) W3b[i] = f2b(W3[i]);   // layer-3 stays linear
}

// Hierarchical compaction: wave ballot -> LDS atomics -> 4 global atomics/block.
__global__ __launch_bounds__(1024) void compact_kernel(
    const int* __restrict__ z, int* __restrict__ cnt,
    int* __restrict__ lists, float* __restrict__ out) {
    __shared__ int lcnt[4];
    __shared__ int gbase[4];
    __shared__ int wbase[16][4];

    int tid = threadIdx.x;
    int wv = tid >> 6;
    int lane = tid & 63;
    if (tid < 4) lcnt[tid] = 0;
    __syncthreads();

    int i = blockIdx.x * 1024 + tid;
    int zz = z[i];
    int s = (zz == 1) ? 0 : (zz == 6) ? 1 : (zz == 7) ? 2 : (zz == 8) ? 3 : -1;
    if (s < 0) out[i] = 0.f;

    int prefix = 0;
#pragma unroll
    for (int sp = 0; sp < 4; ++sp) {
        unsigned long long m = __ballot(s == sp);
        if (m) {
            int c = __popcll(m);
            int leader = __ffsll((long long)m) - 1;
            if (lane == leader) wbase[wv][sp] = atomicAdd(&lcnt[sp], c);
            if (s == sp) prefix = __popcll(m & ((1ull << lane) - 1ull));
        }
    }
    __syncthreads();
    if (tid < 4) gbase[tid] = atomicAdd(&cnt[tid], lcnt[tid]);
    __syncthreads();

    if (s >= 0) lists[s * NATOMS + gbase[s] + wbase[wv][s] + prefix] = i;
}

// MT=4 M-tiles (64 rows), NT=2 N-tiles (32 cols) per wave. Packed-B pointers.
template<int K, int LDB, int NT>
__device__ __forceinline__ void gemm_layer(const char* lds, const us* Wp,
                                           int lane, int wtile, f32x4 acc[4][NT]) {
    constexpr int KS = K / 32;
    const us* wptr[NT];
#pragma unroll
    for (int nt = 0; nt < NT; ++nt)
        wptr[nt] = Wp + (((size_t)(wtile + nt) * KS) * 64 + lane) * 8;
    for (int k0 = 0; k0 < K; k0 += 32) {
        bf16x8 a[4];
#pragma unroll
        for (int mt = 0; mt < 4; ++mt) {
            int row = mt * 16 + (lane & 15);
            int colb = (k0 + ((lane >> 4) << 3)) * 2;
            a[mt] = *(const bf16x8*)(lds + row * LDB + (colb ^ ((row & 7) << 4)));
        }
        bf16x8 bfr[NT];
#pragma unroll
        for (int nt = 0; nt < NT; ++nt) {
            bfr[nt] = *(const bf16x8*)wptr[nt];
            wptr[nt] += 512;     // 64 chunks * 8 shorts per k-step
        }
#pragma unroll
        for (int nt = 0; nt < NT; ++nt)
#pragma unroll
            for (int mt = 0; mt < 4; ++mt)
                acc[mt][nt] = __builtin_amdgcn_mfma_f32_16x16x32_bf16(a[mt], bfr[nt], acc[mt][nt], 0, 0, 0);
    }
}

template<int LDB, int NT>
__device__ __forceinline__ void act_store(char* ldsOut, const float* __restrict__ bias,
                                          int lane, int ncb, f32x4 acc[4][NT]) {
#pragma unroll
    for (int nt = 0; nt < NT; ++nt) {
        int n = ncb + nt * 16 + (lane & 15);
        float bv = bias[n];
#pragma unroll
        for (int mt = 0; mt < 4; ++mt) {
#pragma unroll
            for (int r = 0; r < 4; ++r) {
                int row = mt * 16 + ((lane >> 4) << 2) + r;
                float v = fast_tanh(acc[mt][nt][r] + bv);
                *(us*)(ldsOut + row * LDB + (((n * 2) ^ ((row & 7) << 4)))) = f2b(v);
            }
        }
    }
}

// TM=64, 1024 thr (16 waves), 64 KB LDS: 2 blocks/CU, 8 waves/SIMD.
// Per-wave frags: acc[4][2]=32 + a[4]=16 + b[2]=8 regs -> fits 64-VGPR cap.
// Halves per-atom L2 weight traffic vs TM=32 (768 KB per 64 atoms).
__global__ __launch_bounds__(1024, 8) void mlp_kernel(
    const float* __restrict__ x, const int* __restrict__ cnt, const int* __restrict__ lists,
    const us* __restrict__ W1p, const us* __restrict__ W2p, const us* __restrict__ W3b,
    const float* __restrict__ b1, const float* __restrict__ b2, const float* __restrict__ b3,
    float* __restrict__ out) {
    int bx = blockIdx.x;
    int s = bx & 3;
    int t = bx >> 2;
    int base = t * TM;
    int n_s = cnt[s];
    if (base >= n_s) return;
    const int* list = lists + s * NATOMS;
    int cnt_t = n_s - base; if (cnt_t > TM) cnt_t = TM;

    __shared__ __align__(16) char lds[TM * NHID * 2];   // 64 KB: x-tile, then h1, then h2

    int tid = threadIdx.x;
    int lane = tid & 63;
    int w = tid >> 6;            // 0..15
    int ncb = w * 32;            // wave's 32-col slice
    int wtile = w * 2;           // base 16-col tile index

    // ---- gather x rows -> bf16 LDS (swizzled, 512B rows): 16 thr/row, 4 float4 ----
    {
        int r = tid >> 4;            // 0..63
        int cb = (tid & 15) * 16;    // col base (floats)
        int atom = (r < cnt_t) ? list[base + r] : -1;
        const float* xr = x + (size_t)(atom < 0 ? 0 : atom) * NIN;
#pragma unroll
        for (int j = 0; j < 4; ++j) {
            int c = cb + j * 4;
            float4 v;
            if (atom >= 0) v = *(const float4*)(xr + c);
            else v = make_float4(0.f, 0.f, 0.f, 0.f);
            us p[4] = { f2b(v.x), f2b(v.y), f2b(v.z), f2b(v.w) };
            int off = r * (NIN * 2) + (((c * 2) ^ ((r & 7) << 4)));
            *(unsigned long long*)(lds + off) = *(unsigned long long*)p;
        }
    }
    __syncthreads();

    // ---- layer 1: [64x256] x [256x512]^T -> h1 ----
    {
        f32x4 acc[4][2];
#pragma unroll
        for (int i = 0; i < 4; ++i)
#pragma unroll
            for (int j = 0; j < 2; ++j) acc[i][j] = (f32x4){0.f, 0.f, 0.f, 0.f};
        gemm_layer<NIN, NIN * 2, 2>(lds, W1p + (size_t)s * NHID * NIN, lane, wtile, acc);
        __syncthreads();   // x-tile fully consumed before h1 overwrites it
        act_store<NHID * 2, 2>(lds, b1 + s * NHID, lane, ncb, acc);
    }
    __syncthreads();

    // ---- layer 2: [64x512] x [512x512]^T -> h2 (in place) ----
    {
        f32x4 acc[4][2];
#pragma unroll
        for (int i = 0; i < 4; ++i)
#pragma unroll
            for (int j = 0; j < 2; ++j) acc[i][j] = (f32x4){0.f, 0.f, 0.f, 0.f};
        gemm_layer<NHID, NHID * 2, 2>(lds, W2p + (size_t)s * NHID * NHID, lane, wtile, acc);
        __syncthreads();   // h1 fully consumed before h2 overwrites it
        act_store<NHID * 2, 2>(lds, b2 + s * NHID, lane, ncb, acc);
    }
    __syncthreads();

    // ---- layer 3: out[m] = dot(h2[m,:], W3[s]) + b3[s]; 16 thr/row ----
    {
        int m = tid >> 4;        // 0..63
        int q = tid & 15;        // 32-col slice
        const us* W3s = W3b + (size_t)s * NHID;
        float sum = 0.f;
#pragma unroll
        for (int j = 0; j < 4; ++j) {
            int hh = q * 32 + j * 8;
            int off = m * (NHID * 2) + (((hh * 2) ^ ((m & 7) << 4)));
            bf16x8 hv = *(const bf16x8*)(lds + off);
            bf16x8 wv = *(const bf16x8*)(W3s + hh);
#pragma unroll
            for (int e = 0; e < 8; ++e)
                sum += b2f((us)hv[e]) * b2f((us)wv[e]);
        }
        sum += __shfl_xor(sum, 1);
        sum += __shfl_xor(sum, 2);
        sum += __shfl_xor(sum, 4);
        sum += __shfl_xor(sum, 8);
        if (q == 0 && m < cnt_t) out[list[base + m]] = sum + b3[s];
    }
}

extern "C" void kernel_launch(void* const* d_in, const int* in_sizes, int n_in,
                              void* d_out, int out_size, void* d_ws, size_t ws_size,
                              hipStream_t stream) {
    const float* x  = (const float*)d_in[0];
    const int*   z  = (const int*)d_in[1];
    const float* W1 = (const float*)d_in[2];
    const float* b1 = (const float*)d_in[3];
    const float* W2 = (const float*)d_in[4];
    const float* b2 = (const float*)d_in[5];
    const float* W3 = (const float*)d_in[6];
    const float* b3 = (const float*)d_in[7];
    float* out = (float*)d_out;

    char* ws = (char*)d_ws;
    int* cnt = (int*)ws;                                      // 16 B
    int* lists = (int*)(ws + 256);                            // 1 MB
    us* W1p = (us*)(ws + 256 + (size_t)4 * NATOMS * 4);       // 1 MB
    us* W2p = W1p + 4 * NHID * NIN;                           // 2 MB
    us* W3b = W2p + 4 * NHID * NHID;                          // 4 KB

    hipMemsetAsync(cnt, 0, 16, stream);
    cvt_kernel<<<512, 256, 0, stream>>>(W1, W2, W3, W1p, W2p, W3b);
    compact_kernel<<<NATOMS / 1024, 1024, 0, stream>>>(z, cnt, lists, out);
    mlp_kernel<<<4096, 1024, 0, stream>>>(x, cnt, lists, W1p, W2p, W3b, b1, b2, b3, out);
}

// Round 9
// 73.704 us; speedup vs baseline: 1.2971x; 1.2971x over previous
//
#include <hip/hip_runtime.h>

typedef __attribute__((ext_vector_type(8))) short bf16x8;
typedef __attribute__((ext_vector_type(4))) float f32x4;
typedef unsigned short us;

#define NATOMS 65536
#define NIN 256
#define NHID 512
#define TM 64

__device__ __forceinline__ us f2b(float f) {
    union { float f; unsigned int u; } a; a.f = f;
    unsigned int r = a.u + 0x7FFFu + ((a.u >> 16) & 1u);
    return (us)(r >> 16);
}
__device__ __forceinline__ float b2f(us h) {
    union { unsigned int u; float f; } a; a.u = ((unsigned int)h) << 16;
    return a.f;
}
__device__ __forceinline__ float fast_tanh(float v) {
    float e = __expf(2.f * v);
    return 1.f - 2.f / (e + 1.f);
}

// Pack W1/W2 into MFMA-fragment order: chunk[(ntile*KS + kstep)*64 + lane] =
// W[n= ntile*16+(lane&15)][k= kstep*32+(lane>>4)*8 .. +8) as bf16x8.
__global__ void cvt_kernel(const float* __restrict__ W1, const float* __restrict__ W2,
                           const float* __restrict__ W3,
                           us* __restrict__ W1p, us* __restrict__ W2p,
                           us* __restrict__ W3b) {
    int i = blockIdx.x * blockDim.x + threadIdx.x;
    if (i < 65536) {               // W1: 4 species * 32 ntiles * 8 ksteps * 64 lanes
        int s = i >> 14, rem = i & 16383;
        int ntile = rem >> 9, r2 = rem & 511;
        int kstep = r2 >> 6, lane = r2 & 63;
        int n = ntile * 16 + (lane & 15);
        int k = kstep * 32 + ((lane >> 4) << 3);
        const float* src = W1 + ((size_t)(s * NHID + n) * NIN + k);
        us p[8];
#pragma unroll
        for (int j = 0; j < 8; ++j) p[j] = f2b(src[j]);
        *(uint4*)(W1p + (size_t)i * 8) = *(uint4*)p;
    }
    if (i < 131072) {              // W2: 4 * 32 * 16 * 64
        int s = i >> 15, rem = i & 32767;
        int ntile = rem >> 10, r2 = rem & 1023;
        int kstep = r2 >> 6, lane = r2 & 63;
        int n = ntile * 16 + (lane & 15);
        int k = kstep * 32 + ((lane >> 4) << 3);
        const float* src = W2 + ((size_t)(s * NHID + n) * NHID + k);
        us p[8];
#pragma unroll
        for (int j = 0; j < 8; ++j) p[j] = f2b(src[j]);
        *(uint4*)(W2p + (size_t)i * 8) = *(uint4*)p;
    }
    if (i < 2048) W3b[i] = f2b(W3[i]);   // layer-3 stays linear
}

// Hierarchical compaction: wave ballot -> LDS atomics -> 4 global atomics/block.
__global__ __launch_bounds__(1024) void compact_kernel(
    const int* __restrict__ z, int* __restrict__ cnt,
    int* __restrict__ lists, float* __restrict__ out) {
    __shared__ int lcnt[4];
    __shared__ int gbase[4];
    __shared__ int wbase[16][4];

    int tid = threadIdx.x;
    int wv = tid >> 6;
    int lane = tid & 63;
    if (tid < 4) lcnt[tid] = 0;
    __syncthreads();

    int i = blockIdx.x * 1024 + tid;
    int zz = z[i];
    int s = (zz == 1) ? 0 : (zz == 6) ? 1 : (zz == 7) ? 2 : (zz == 8) ? 3 : -1;
    if (s < 0) out[i] = 0.f;

    int prefix = 0;
#pragma unroll
    for (int sp = 0; sp < 4; ++sp) {
        unsigned long long m = __ballot(s == sp);
        if (m) {
            int c = __popcll(m);
            int leader = __ffsll((long long)m) - 1;
            if (lane == leader) wbase[wv][sp] = atomicAdd(&lcnt[sp], c);
            if (s == sp) prefix = __popcll(m & ((1ull << lane) - 1ull));
        }
    }
    __syncthreads();
    if (tid < 4) gbase[tid] = atomicAdd(&cnt[tid], lcnt[tid]);
    __syncthreads();

    if (s >= 0) lists[s * NATOMS + gbase[s] + wbase[wv][s] + prefix] = i;
}

// MT=4 M-tiles (64 rows), NT=2 N-tiles (32 cols) per pass. Packed-B pointers.
template<int K, int LDB>
__device__ __forceinline__ void gemm_pass(const char* lds, const us* Wp,
                                          int lane, int wtile, f32x4 acc[4][2]) {
    constexpr int KS = K / 32;
    const us* wptr0 = Wp + (((size_t)(wtile + 0) * KS) * 64 + lane) * 8;
    const us* wptr1 = Wp + (((size_t)(wtile + 1) * KS) * 64 + lane) * 8;
    for (int k0 = 0; k0 < K; k0 += 32) {
        bf16x8 a[4];
#pragma unroll
        for (int mt = 0; mt < 4; ++mt) {
            int row = mt * 16 + (lane & 15);
            int colb = (k0 + ((lane >> 4) << 3)) * 2;
            a[mt] = *(const bf16x8*)(lds + row * LDB + (colb ^ ((row & 7) << 4)));
        }
        bf16x8 b0 = *(const bf16x8*)wptr0; wptr0 += 512;
        bf16x8 b1 = *(const bf16x8*)wptr1; wptr1 += 512;
#pragma unroll
        for (int mt = 0; mt < 4; ++mt)
            acc[mt][0] = __builtin_amdgcn_mfma_f32_16x16x32_bf16(a[mt], b0, acc[mt][0], 0, 0, 0);
#pragma unroll
        for (int mt = 0; mt < 4; ++mt)
            acc[mt][1] = __builtin_amdgcn_mfma_f32_16x16x32_bf16(a[mt], b1, acc[mt][1], 0, 0, 0);
    }
}

template<int LDB>
__device__ __forceinline__ void act_store(char* ldsOut, const float* __restrict__ bias,
                                          int lane, int ncb, f32x4 acc[4][2]) {
#pragma unroll
    for (int nt = 0; nt < 2; ++nt) {
        int n = ncb + nt * 16 + (lane & 15);
        float bv = bias[n];
#pragma unroll
        for (int mt = 0; mt < 4; ++mt) {
#pragma unroll
            for (int r = 0; r < 4; ++r) {
                int row = mt * 16 + ((lane >> 4) << 2) + r;
                float v = fast_tanh(acc[mt][nt][r] + bv);
                *(us*)(ldsOut + row * LDB + (((n * 2) ^ ((row & 7) << 4)))) = f2b(v);
            }
        }
    }
}

// TM=64, 512 thr (8 waves), 96 KB LDS (1 block/CU), (512,2).
// Each layer = two sequential 32-col passes per wave: acc stays at 32 VGPR
// (no spill), and each weight read is amortized over 64 atoms (2x R6).
// Layer-2 pass-0 output stages into ldsX (free after layer 1); pass-1
// writes ldsH in place after the sync. Layer 3 reads the split h2.
__global__ __launch_bounds__(512, 2) void mlp_kernel(
    const float* __restrict__ x, const int* __restrict__ cnt, const int* __restrict__ lists,
    const us* __restrict__ W1p, const us* __restrict__ W2p, const us* __restrict__ W3b,
    const float* __restrict__ b1, const float* __restrict__ b2, const float* __restrict__ b3,
    float* __restrict__ out) {
    int bx = blockIdx.x;
    int s = bx & 3;
    int t = bx >> 2;
    int base = t * TM;
    int n_s = cnt[s];
    if (base >= n_s) return;
    const int* list = lists + s * NATOMS;
    int cnt_t = n_s - base; if (cnt_t > TM) cnt_t = TM;

    __shared__ __align__(16) char ldsX[TM * NIN * 2];   // 32 KB
    __shared__ __align__(16) char ldsH[TM * NHID * 2];  // 64 KB

    int tid = threadIdx.x;
    int lane = tid & 63;
    int w = tid >> 6;            // 0..7

    // ---- gather x rows -> bf16 LDS (swizzled, 512B rows): 8 thr/row ----
    {
        int r = tid >> 3;            // 0..63
        int cb = (tid & 7) * 32;     // col base (floats)
        int atom = (r < cnt_t) ? list[base + r] : -1;
        const float* xr = x + (size_t)(atom < 0 ? 0 : atom) * NIN;
#pragma unroll
        for (int j = 0; j < 8; ++j) {
            int c = cb + j * 4;
            float4 v;
            if (atom >= 0) v = *(const float4*)(xr + c);
            else v = make_float4(0.f, 0.f, 0.f, 0.f);
            us p[4] = { f2b(v.x), f2b(v.y), f2b(v.z), f2b(v.w) };
            int off = r * (NIN * 2) + (((c * 2) ^ ((r & 7) << 4)));
            *(unsigned long long*)(ldsX + off) = *(unsigned long long*)p;
        }
    }
    __syncthreads();

    // ---- layer 1: two sequential 32-col passes; h1 -> ldsH ----
#pragma unroll
    for (int h = 0; h < 2; ++h) {
        f32x4 acc[4][2];
#pragma unroll
        for (int i = 0; i < 4; ++i)
#pragma unroll
            for (int j = 0; j < 2; ++j) acc[i][j] = (f32x4){0.f, 0.f, 0.f, 0.f};
        gemm_pass<NIN, NIN * 2>(ldsX, W1p + (size_t)s * NHID * NIN, lane, w * 4 + h * 2, acc);
        act_store<NHID * 2>(ldsH, b1 + s * NHID, lane, w * 64 + h * 32, acc);
    }
    __syncthreads();

    // ---- layer 2: pass0 -> ldsX (cols 0-255), sync, pass1 -> ldsH in place ----
#pragma unroll
    for (int h = 0; h < 2; ++h) {
        f32x4 acc[4][2];
#pragma unroll
        for (int i = 0; i < 4; ++i)
#pragma unroll
            for (int j = 0; j < 2; ++j) acc[i][j] = (f32x4){0.f, 0.f, 0.f, 0.f};
        gemm_pass<NHID, NHID * 2>(ldsH, W2p + (size_t)s * NHID * NHID, lane, h * 16 + w * 2, acc);
        if (h == 0) {
            act_store<NIN * 2>(ldsX, b2 + s * NHID, lane, w * 32, acc);
        } else {
            __syncthreads();   // all h1 reads done before overwrite
            act_store<NHID * 2>(ldsH, b2 + s * NHID, lane, 256 + w * 32, acc);
        }
    }
    __syncthreads();

    // ---- layer 3: cols 0-255 in ldsX, cols 256-511 in ldsH ----
    {
        int m = tid >> 3;        // 0..63
        int q = tid & 7;         // 64-col eighth
        const us* W3s = W3b + (size_t)s * NHID;
        float sum = 0.f;
#pragma unroll
        for (int j = 0; j < 8; ++j) {
            int hh = q * 64 + j * 8;
            bf16x8 hv;
            if (hh < 256) {
                int off = m * (NIN * 2) + (((hh * 2) ^ ((m & 7) << 4)));
                hv = *(const bf16x8*)(ldsX + off);
            } else {
                int off = m * (NHID * 2) + (((hh * 2) ^ ((m & 7) << 4)));
                hv = *(const bf16x8*)(ldsH + off);
            }
            bf16x8 wv = *(const bf16x8*)(W3s + hh);
#pragma unroll
            for (int e = 0; e < 8; ++e)
                sum += b2f((us)hv[e]) * b2f((us)wv[e]);
        }
        sum += __shfl_xor(sum, 1);
        sum += __shfl_xor(sum, 2);
        sum += __shfl_xor(sum, 4);
        if (q == 0 && m < cnt_t) out[list[base + m]] = sum + b3[s];
    }
}

extern "C" void kernel_launch(void* const* d_in, const int* in_sizes, int n_in,
                              void* d_out, int out_size, void* d_ws, size_t ws_size,
                              hipStream_t stream) {
    const float* x  = (const float*)d_in[0];
    const int*   z  = (const int*)d_in[1];
    const float* W1 = (const float*)d_in[2];
    const float* b1 = (const float*)d_in[3];
    const float* W2 = (const float*)d_in[4];
    const float* b2 = (const float*)d_in[5];
    const float* W3 = (const float*)d_in[6];
    const float* b3 = (const float*)d_in[7];
    float* out = (float*)d_out;

    char* ws = (char*)d_ws;
    int* cnt = (int*)ws;                                      // 16 B
    int* lists = (int*)(ws + 256);                            // 1 MB
    us* W1p = (us*)(ws + 256 + (size_t)4 * NATOMS * 4);       // 1 MB
    us* W2p = W1p + 4 * NHID * NIN;                           // 2 MB
    us* W3b = W2p + 4 * NHID * NHID;                          // 4 KB

    hipMemsetAsync(cnt, 0, 16, stream);
    cvt_kernel<<<512, 256, 0, stream>>>(W1, W2, W3, W1p, W2p, W3b);
    compact_kernel<<<NATOMS / 1024, 1024, 0, stream>>>(z, cnt, lists, out);
    mlp_kernel<<<4096, 512, 0, stream>>>(x, cnt, lists, W1p, W2p, W3b, b1, b2, b3, out);
}

// Round 11
// 63.884 us; speedup vs baseline: 1.4964x; 1.1537x over previous
//
#include <hip/hip_runtime.h>

typedef __attribute__((ext_vector_type(8))) short bf16x8;
typedef __attribute__((ext_vector_type(4))) float f32x4;
typedef __attribute__((ext_vector_type(2))) unsigned int u32x2;
typedef unsigned short us;

#define NATOMS 65536
#define NIN 256
#define NHID 512
#define TM 64
#define LDBX 528    // 256 bf16 cols * 2B + 16B pad: bank base = 4*row mod 32, 2-way free
#define LDBH 1040   // 512 bf16 cols * 2B + 16B pad

__device__ __forceinline__ us f2b(float f) {
    union { float f; unsigned int u; } a; a.f = f;
    unsigned int r = a.u + 0x7FFFu + ((a.u >> 16) & 1u);
    return (us)(r >> 16);
}
__device__ __forceinline__ float fast_tanh(float v) {
    // tanh(x) = 1 - 2/(exp2(x*2*log2e)+1); v_exp_f32 computes 2^x.
    float t = __builtin_amdgcn_exp2f(v * 2.88539008f);
    float r = __builtin_amdgcn_rcpf(t + 1.f);
    return __builtin_fmaf(-2.f, r, 1.f);
}
__device__ __forceinline__ unsigned cvt_pk(float lo, float hi) {
    unsigned p;
    asm("v_cvt_pk_bf16_f32 %0, %1, %2" : "=v"(p) : "v"(lo), "v"(hi));
    return p;
}

// Pack W1/W2 into MFMA-fragment order: chunk[(ntile*KS + kstep)*64 + lane] =
// W[n= ntile*16+(lane&15)][k= kstep*32+(lane>>4)*8 .. +8) as bf16x8.
__global__ void cvt_kernel(const float* __restrict__ W1, const float* __restrict__ W2,
                           const float* __restrict__ W3,
                           us* __restrict__ W1p, us* __restrict__ W2p,
                           us* __restrict__ W3b) {
    int i = blockIdx.x * blockDim.x + threadIdx.x;
    if (i < 65536) {               // W1: 4 species * 32 ntiles * 8 ksteps * 64 lanes
        int s = i >> 14, rem = i & 16383;
        int ntile = rem >> 9, r2 = rem & 511;
        int kstep = r2 >> 6, lane = r2 & 63;
        int n = ntile * 16 + (lane & 15);
        int k = kstep * 32 + ((lane >> 4) << 3);
        const float* src = W1 + ((size_t)(s * NHID + n) * NIN + k);
        us p[8];
#pragma unroll
        for (int j = 0; j < 8; ++j) p[j] = f2b(src[j]);
        *(uint4*)(W1p + (size_t)i * 8) = *(uint4*)p;
    }
    if (i < 131072) {              // W2: 4 * 32 * 16 * 64
        int s = i >> 15, rem = i & 32767;
        int ntile = rem >> 10, r2 = rem & 1023;
        int kstep = r2 >> 6, lane = r2 & 63;
        int n = ntile * 16 + (lane & 15);
        int k = kstep * 32 + ((lane >> 4) << 3);
        const float* src = W2 + ((size_t)(s * NHID + n) * NHID + k);
        us p[8];
#pragma unroll
        for (int j = 0; j < 8; ++j) p[j] = f2b(src[j]);
        *(uint4*)(W2p + (size_t)i * 8) = *(uint4*)p;
    }
    if (i < 2048) W3b[i] = f2b(W3[i]);   // layer-3 stays linear
}

// Hierarchical compaction: wave ballot -> LDS atomics -> 4 global atomics/block.
__global__ __launch_bounds__(1024) void compact_kernel(
    const int* __restrict__ z, int* __restrict__ cnt,
    int* __restrict__ lists, float* __restrict__ out) {
    __shared__ int lcnt[4];
    __shared__ int gbase[4];
    __shared__ int wbase[16][4];

    int tid = threadIdx.x;
    int wv = tid >> 6;
    int lane = tid & 63;
    if (tid < 4) lcnt[tid] = 0;
    __syncthreads();

    int i = blockIdx.x * 1024 + tid;
    int zz = z[i];
    int s = (zz == 1) ? 0 : (zz == 6) ? 1 : (zz == 7) ? 2 : (zz == 8) ? 3 : -1;
    if (s < 0) out[i] = 0.f;

    int prefix = 0;
#pragma unroll
    for (int sp = 0; sp < 4; ++sp) {
        unsigned long long m = __ballot(s == sp);
        if (m) {
            int c = __popcll(m);
            int leader = __ffsll((long long)m) - 1;
            if (lane == leader) wbase[wv][sp] = atomicAdd(&lcnt[sp], c);
            if (s == sp) prefix = __popcll(m & ((1ull << lane) - 1ull));
        }
    }
    __syncthreads();
    if (tid < 4) gbase[tid] = atomicAdd(&cnt[tid], lcnt[tid]);
    __syncthreads();

    if (s >= 0) lists[s * NATOMS + gbase[s] + wbase[wv][s] + prefix] = i;
}

// MT=4 (64 rows), NT=2 (32 cols) per pass. Padded LDS (addresses linear in
// kstep -> immediate offsets) + 2-stage register prefetch of A (LDS) and
// B (L2) to hide latency at low occupancy.
template<int K, int LDB>
__device__ __forceinline__ void gemm_pass(const char* lds, const us* Wp,
                                          int lane, int wtile, f32x4 acc[4][2]) {
    constexpr int KS = K / 32;
    const us* wp0 = Wp + (((size_t)(wtile + 0) * KS) * 64 + lane) * 8;
    const us* wp1 = Wp + (((size_t)(wtile + 1) * KS) * 64 + lane) * 8;
    int aoff[4];
#pragma unroll
    for (int mt = 0; mt < 4; ++mt)
        aoff[mt] = (mt * 16 + (lane & 15)) * LDB + (((lane >> 4) << 3) << 1);

    bf16x8 a[2][4], b0[2], b1[2];
#pragma unroll
    for (int mt = 0; mt < 4; ++mt) a[0][mt] = *(const bf16x8*)(lds + aoff[mt]);
    b0[0] = *(const bf16x8*)wp0;
    b1[0] = *(const bf16x8*)wp1;

#pragma unroll
    for (int i = 0; i < KS; ++i) {
        const int cur = i & 1, nxt = cur ^ 1;
        if (i + 1 < KS) {
#pragma unroll
            for (int mt = 0; mt < 4; ++mt)
                a[nxt][mt] = *(const bf16x8*)(lds + aoff[mt] + (i + 1) * 64);
            b0[nxt] = *(const bf16x8*)(wp0 + (i + 1) * 512);
            b1[nxt] = *(const bf16x8*)(wp1 + (i + 1) * 512);
        }
#pragma unroll
        for (int mt = 0; mt < 4; ++mt)
            acc[mt][0] = __builtin_amdgcn_mfma_f32_16x16x32_bf16(a[cur][mt], b0[cur], acc[mt][0], 0, 0, 0);
#pragma unroll
        for (int mt = 0; mt < 4; ++mt)
            acc[mt][1] = __builtin_amdgcn_mfma_f32_16x16x32_bf16(a[cur][mt], b1[cur], acc[mt][1], 0, 0, 0);
    }
}

template<int LDB>
__device__ __forceinline__ void act_store(char* ldsOut, const float* __restrict__ bias,
                                          int lane, int ncb, f32x4 acc[4][2]) {
#pragma unroll
    for (int nt = 0; nt < 2; ++nt) {
        int n = ncb + nt * 16 + (lane & 15);
        float bv = bias[n];
#pragma unroll
        for (int mt = 0; mt < 4; ++mt) {
            float t0 = fast_tanh(acc[mt][nt][0] + bv);
            float t1 = fast_tanh(acc[mt][nt][1] + bv);
            float t2 = fast_tanh(acc[mt][nt][2] + bv);
            float t3 = fast_tanh(acc[mt][nt][3] + bv);
            unsigned p01 = cvt_pk(t0, t1);
            unsigned p23 = cvt_pk(t2, t3);
            int row0 = mt * 16 + ((lane >> 4) << 2);
            char* base = ldsOut + row0 * LDB + n * 2;
            *(us*)(base)           = (us)p01;
            *(us*)(base + LDB)     = (us)(p01 >> 16);
            *(us*)(base + 2 * LDB) = (us)p23;
            *(us*)(base + 3 * LDB) = (us)(p23 >> 16);
        }
    }
}

// TM=64, 512 thr (8 waves), 98 KB padded LDS (1 block/CU), no VGPR cap.
// Layer = two sequential 32-col passes/wave (acc stays 32 VGPR). Layer-2
// pass0 stages into ldsX (dead after layer 1); pass1 in-place after sync.
__global__ __launch_bounds__(512, 2) void mlp_kernel(
    const float* __restrict__ x, const int* __restrict__ cnt, const int* __restrict__ lists,
    const us* __restrict__ W1p, const us* __restrict__ W2p, const us* __restrict__ W3b,
    const float* __restrict__ b1, const float* __restrict__ b2, const float* __restrict__ b3,
    float* __restrict__ out) {
    int bx = blockIdx.x;
    int s = bx & 3;          // species fixed per XCD (bx%8): weights stay hot in its L2
    int t = bx >> 2;
    int base = t * TM;
    int n_s = cnt[s];
    if (base >= n_s) return;
    const int* list = lists + s * NATOMS;
    int cnt_t = n_s - base; if (cnt_t > TM) cnt_t = TM;

    __shared__ __align__(16) char ldsX[TM * LDBX];   // 33 KB
    __shared__ __align__(16) char ldsH[TM * LDBH];   // 65 KB

    int tid = threadIdx.x;
    int lane = tid & 63;
    int w = tid >> 6;            // 0..7

    // ---- gather x rows -> bf16 LDS (padded rows): 8 thr/row, 8 float4 each ----
    {
        int r = tid >> 3;            // 0..63
        int cb = (tid & 7) * 32;     // col base (floats)
        int atom = (r < cnt_t) ? list[base + r] : -1;
        const float* xr = x + (size_t)(atom < 0 ? 0 : atom) * NIN;
#pragma unroll
        for (int j = 0; j < 8; ++j) {
            int c = cb + j * 4;
            float4 v;
            if (atom >= 0) v = *(const float4*)(xr + c);
            else v = make_float4(0.f, 0.f, 0.f, 0.f);
            u32x2 p;
            p.x = cvt_pk(v.x, v.y);
            p.y = cvt_pk(v.z, v.w);
            *(u32x2*)(ldsX + r * LDBX + c * 2) = p;
        }
    }
    __syncthreads();

    // ---- layer 1: two sequential 32-col passes; h1 -> ldsH ----
#pragma unroll
    for (int h = 0; h < 2; ++h) {
        f32x4 acc[4][2];
#pragma unroll
        for (int i = 0; i < 4; ++i)
#pragma unroll
            for (int j = 0; j < 2; ++j) acc[i][j] = (f32x4){0.f, 0.f, 0.f, 0.f};
        gemm_pass<NIN, LDBX>(ldsX, W1p + (size_t)s * NHID * NIN, lane, w * 4 + h * 2, acc);
        act_store<LDBH>(ldsH, b1 + s * NHID, lane, w * 64 + h * 32, acc);
    }
    __syncthreads();

    // ---- layer 2: pass0 -> ldsX (cols 0-255), sync, pass1 -> ldsH in place ----
#pragma unroll
    for (int h = 0; h < 2; ++h) {
        f32x4 acc[4][2];
#pragma unroll
        for (int i = 0; i < 4; ++i)
#pragma unroll
            for (int j = 0; j < 2; ++j) acc[i][j] = (f32x4){0.f, 0.f, 0.f, 0.f};
        gemm_pass<NHID, LDBH>(ldsH, W2p + (size_t)s * NHID * NHID, lane, h * 16 + w * 2, acc);
        if (h == 0) {
            act_store<LDBX>(ldsX, b2 + s * NHID, lane, w * 32, acc);
        } else {
            __syncthreads();   // all h1 reads done before overwrite
            act_store<LDBH>(ldsH, b2 + s * NHID, lane, 256 + w * 32, acc);
        }
    }
    __syncthreads();

    // ---- layer 3: cols 0-255 in ldsX, cols 256-511 in ldsH ----
    {
        int m = tid >> 3;        // 0..63
        int q = tid & 7;         // 64-col eighth
        const us* W3s = W3b + (size_t)s * NHID;
        float sum = 0.f;
#pragma unroll
        for (int j = 0; j < 8; ++j) {
            int hh = q * 64 + j * 8;
            bf16x8 hv;
            if (hh < 256) hv = *(const bf16x8*)(ldsX + m * LDBX + hh * 2);
            else          hv = *(const bf16x8*)(ldsH + m * LDBH + hh * 2);
            bf16x8 wv = *(const bf16x8*)(W3s + hh);
#pragma unroll
            for (int e = 0; e < 8; ++e) {
                union { unsigned u; float f; } ha, wa;
                ha.u = ((unsigned)(us)hv[e]) << 16;
                wa.u = ((unsigned)(us)wv[e]) << 16;
                sum += ha.f * wa.f;
            }
        }
        sum += __shfl_xor(sum, 1);
        sum += __shfl_xor(sum, 2);
        sum += __shfl_xor(sum, 4);
        if (q == 0 && m < cnt_t) out[list[base + m]] = sum + b3[s];
    }
}

extern "C" void kernel_launch(void* const* d_in, const int* in_sizes, int n_in,
                              void* d_out, int out_size, void* d_ws, size_t ws_size,
                              hipStream_t stream) {
    const float* x  = (const float*)d_in[0];
    const int*   z  = (const int*)d_in[1];
    const float* W1 = (const float*)d_in[2];
    const float* b1 = (const float*)d_in[3];
    const float* W2 = (const float*)d_in[4];
    const float* b2 = (const float*)d_in[5];
    const float* W3 = (const float*)d_in[6];
    const float* b3 = (const float*)d_in[7];
    float* out = (float*)d_out;

    char* ws = (char*)d_ws;
    int* cnt = (int*)ws;                                      // 16 B
    int* lists = (int*)(ws + 256);                            // 1 MB
    us* W1p = (us*)(ws + 256 + (size_t)4 * NATOMS * 4);       // 1 MB
    us* W2p = W1p + 4 * NHID * NIN;                           // 2 MB
    us* W3b = W2p + 4 * NHID * NHID;                          // 4 KB

    (void)hipMemsetAsync(cnt, 0, 16, stream);
    cvt_kernel<<<512, 256, 0, stream>>>(W1, W2, W3, W1p, W2p, W3b);
    compact_kernel<<<NATOMS / 1024, 1024, 0, stream>>>(z, cnt, lists, out);
    mlp_kernel<<<4096, 512, 0, stream>>>(x, cnt, lists, W1p, W2p, W3b, b1, b2, b3, out);
}

// Round 12
// 61.993 us; speedup vs baseline: 1.5421x; 1.0305x over previous
//
#include <hip/hip_runtime.h>

typedef __attribute__((ext_vector_type(8))) short bf16x8;
typedef __attribute__((ext_vector_type(4))) float f32x4;
typedef __attribute__((ext_vector_type(2))) unsigned int u32x2;
typedef unsigned short us;

#define NATOMS 65536
#define NIN 256
#define NHID 512
#define TM 64
#define LDBX 528    // 256 bf16 cols * 2B + 16B pad
#define LDBH 1040   // 512 bf16 cols * 2B + 16B pad

__device__ __forceinline__ us f2b(float f) {
    union { float f; unsigned int u; } a; a.f = f;
    unsigned int r = a.u + 0x7FFFu + ((a.u >> 16) & 1u);
    return (us)(r >> 16);
}
__device__ __forceinline__ float fast_tanh(float v) {
    float t = __builtin_amdgcn_exp2f(v * 2.88539008f);
    float r = __builtin_amdgcn_rcpf(t + 1.f);
    return __builtin_fmaf(-2.f, r, 1.f);
}
__device__ __forceinline__ unsigned cvt_pk(float lo, float hi) {
    unsigned p;
    asm("v_cvt_pk_bf16_f32 %0, %1, %2" : "=v"(p) : "v"(lo), "v"(hi));
    return p;
}

// Pack W1/W2 into MFMA-fragment order: chunk[(ntile*KS + kstep)*64 + lane] =
// W[n= ntile*16+(lane&15)][k= kstep*32+(lane>>4)*8 .. +8) as bf16x8.
__global__ void cvt_kernel(const float* __restrict__ W1, const float* __restrict__ W2,
                           const float* __restrict__ W3,
                           us* __restrict__ W1p, us* __restrict__ W2p,
                           us* __restrict__ W3b) {
    int i = blockIdx.x * blockDim.x + threadIdx.x;
    if (i < 65536) {               // W1: 4 species * 32 ntiles * 8 ksteps * 64 lanes
        int s = i >> 14, rem = i & 16383;
        int ntile = rem >> 9, r2 = rem & 511;
        int kstep = r2 >> 6, lane = r2 & 63;
        int n = ntile * 16 + (lane & 15);
        int k = kstep * 32 + ((lane >> 4) << 3);
        const float* src = W1 + ((size_t)(s * NHID + n) * NIN + k);
        us p[8];
#pragma unroll
        for (int j = 0; j < 8; ++j) p[j] = f2b(src[j]);
        *(uint4*)(W1p + (size_t)i * 8) = *(uint4*)p;
    }
    if (i < 131072) {              // W2: 4 * 32 * 16 * 64
        int s = i >> 15, rem = i & 32767;
        int ntile = rem >> 10, r2 = rem & 1023;
        int kstep = r2 >> 6, lane = r2 & 63;
        int n = ntile * 16 + (lane & 15);
        int k = kstep * 32 + ((lane >> 4) << 3);
        const float* src = W2 + ((size_t)(s * NHID + n) * NHID + k);
        us p[8];
#pragma unroll
        for (int j = 0; j < 8; ++j) p[j] = f2b(src[j]);
        *(uint4*)(W2p + (size_t)i * 8) = *(uint4*)p;
    }
    if (i < 2048) W3b[i] = f2b(W3[i]);   // layer-3 stays linear
}

// Hierarchical compaction: wave ballot -> LDS atomics -> 4 global atomics/block.
__global__ __launch_bounds__(1024) void compact_kernel(
    const int* __restrict__ z, int* __restrict__ cnt,
    int* __restrict__ lists, float* __restrict__ out) {
    __shared__ int lcnt[4];
    __shared__ int gbase[4];
    __shared__ int wbase[16][4];

    int tid = threadIdx.x;
    int wv = tid >> 6;
    int lane = tid & 63;
    if (tid < 4) lcnt[tid] = 0;
    __syncthreads();

    int i = blockIdx.x * 1024 + tid;
    int zz = z[i];
    int s = (zz == 1) ? 0 : (zz == 6) ? 1 : (zz == 7) ? 2 : (zz == 8) ? 3 : -1;
    if (s < 0) out[i] = 0.f;

    int prefix = 0;
#pragma unroll
    for (int sp = 0; sp < 4; ++sp) {
        unsigned long long m = __ballot(s == sp);
        if (m) {
            int c = __popcll(m);
            int leader = __ffsll((long long)m) - 1;
            if (lane == leader) wbase[wv][sp] = atomicAdd(&lcnt[sp], c);
            if (s == sp) prefix = __popcll(m & ((1ull << lane) - 1ull));
        }
    }
    __syncthreads();
    if (tid < 4) gbase[tid] = atomicAdd(&cnt[tid], lcnt[tid]);
    __syncthreads();

    if (s >= 0) lists[s * NATOMS + gbase[s] + wbase[wv][s] + prefix] = i;
}

// Single-pass GEMM: MT=4 (64 rows) x NT=4 (64 cols) per wave.
// 16 MFMA per k-step on 4 A ds_reads + 4 packed-B loads (each A-frag read
// once per layer). 2-stage register prefetch of A (LDS) and B (L2).
template<int K, int LDB>
__device__ __forceinline__ void gemm4(const char* lds, const us* Wp,
                                      int lane, int wtile, f32x4 acc[4][4]) {
    constexpr int KS = K / 32;
    const us* wp[4];
#pragma unroll
    for (int nt = 0; nt < 4; ++nt)
        wp[nt] = Wp + (((size_t)(wtile + nt) * KS) * 64 + lane) * 8;
    int aoff[4];
#pragma unroll
    for (int mt = 0; mt < 4; ++mt)
        aoff[mt] = (mt * 16 + (lane & 15)) * LDB + (((lane >> 4) << 3) << 1);

    bf16x8 a[2][4], b[2][4];
#pragma unroll
    for (int mt = 0; mt < 4; ++mt) a[0][mt] = *(const bf16x8*)(lds + aoff[mt]);
#pragma unroll
    for (int nt = 0; nt < 4; ++nt) b[0][nt] = *(const bf16x8*)wp[nt];

#pragma unroll
    for (int i = 0; i < KS; ++i) {
        const int cur = i & 1, nxt = cur ^ 1;
        if (i + 1 < KS) {
#pragma unroll
            for (int mt = 0; mt < 4; ++mt)
                a[nxt][mt] = *(const bf16x8*)(lds + aoff[mt] + (i + 1) * 64);
#pragma unroll
            for (int nt = 0; nt < 4; ++nt)
                b[nxt][nt] = *(const bf16x8*)(wp[nt] + (i + 1) * 512);
        }
#pragma unroll
        for (int nt = 0; nt < 4; ++nt)
#pragma unroll
            for (int mt = 0; mt < 4; ++mt)
                acc[mt][nt] = __builtin_amdgcn_mfma_f32_16x16x32_bf16(a[cur][mt], b[cur][nt], acc[mt][nt], 0, 0, 0);
    }
}

template<int LDB>
__device__ __forceinline__ void act_store(char* ldsOut, const float* __restrict__ bias,
                                          int lane, int ncb, f32x4 acc[4][4]) {
#pragma unroll
    for (int nt = 0; nt < 4; ++nt) {
        int n = ncb + nt * 16 + (lane & 15);
        float bv = bias[n];
#pragma unroll
        for (int mt = 0; mt < 4; ++mt) {
            float t0 = fast_tanh(acc[mt][nt][0] + bv);
            float t1 = fast_tanh(acc[mt][nt][1] + bv);
            float t2 = fast_tanh(acc[mt][nt][2] + bv);
            float t3 = fast_tanh(acc[mt][nt][3] + bv);
            unsigned p01 = cvt_pk(t0, t1);
            unsigned p23 = cvt_pk(t2, t3);
            int row0 = mt * 16 + ((lane >> 4) << 2);
            char* base = ldsOut + row0 * LDB + n * 2;
            *(us*)(base)           = (us)p01;
            *(us*)(base + LDB)     = (us)(p01 >> 16);
            *(us*)(base + 2 * LDB) = (us)p23;
            *(us*)(base + 3 * LDB) = (us)(p23 >> 16);
        }
    }
}

// TM=64, 512 thr (8 waves), 98 KB LDS (1 block/CU -> 2 waves/SIMD), single
// NT=4 pass per layer. VGPR free to ~256 (8 waves/CU needs <=256/thread):
// acc 64 + frag dbuf ~64 + addr fits without spill. launch_bounds(512,1).
__global__ __launch_bounds__(512, 1) void mlp_kernel(
    const float* __restrict__ x, const int* __restrict__ cnt, const int* __restrict__ lists,
    const us* __restrict__ W1p, const us* __restrict__ W2p, const us* __restrict__ W3b,
    const float* __restrict__ b1, const float* __restrict__ b2, const float* __restrict__ b3,
    float* __restrict__ out) {
    int bx = blockIdx.x;
    int s = bx & 3;          // species fixed per XCD (bx%8): weights stay hot in its L2
    int t = bx >> 2;
    int base = t * TM;
    int n_s = cnt[s];
    if (base >= n_s) return;
    const int* list = lists + s * NATOMS;
    int cnt_t = n_s - base; if (cnt_t > TM) cnt_t = TM;

    __shared__ __align__(16) char ldsX[TM * LDBX];   // 33 KB
    __shared__ __align__(16) char ldsH[TM * LDBH];   // 65 KB

    int tid = threadIdx.x;
    int lane = tid & 63;
    int w = tid >> 6;            // 0..7
    int wtile = w * 4;           // wave's base 16-col tile
    int ncb = w * 64;            // wave's base output column

    // ---- gather x rows -> bf16 LDS (padded rows): 8 thr/row, 8 float4 each ----
    {
        int r = tid >> 3;            // 0..63
        int cb = (tid & 7) * 32;     // col base (floats)
        int atom = (r < cnt_t) ? list[base + r] : -1;
        const float* xr = x + (size_t)(atom < 0 ? 0 : atom) * NIN;
#pragma unroll
        for (int j = 0; j < 8; ++j) {
            int c = cb + j * 4;
            float4 v;
            if (atom >= 0) v = *(const float4*)(xr + c);
            else v = make_float4(0.f, 0.f, 0.f, 0.f);
            u32x2 p;
            p.x = cvt_pk(v.x, v.y);
            p.y = cvt_pk(v.z, v.w);
            *(u32x2*)(ldsX + r * LDBX + c * 2) = p;
        }
    }
    __syncthreads();

    // ---- layer 1: [64x256] x [256x512]^T -> h1 (writes ldsH, no hazard) ----
    {
        f32x4 acc[4][4];
#pragma unroll
        for (int i = 0; i < 4; ++i)
#pragma unroll
            for (int j = 0; j < 4; ++j) acc[i][j] = (f32x4){0.f, 0.f, 0.f, 0.f};
        gemm4<NIN, LDBX>(ldsX, W1p + (size_t)s * NHID * NIN, lane, wtile, acc);
        act_store<LDBH>(ldsH, b1 + s * NHID, lane, ncb, acc);
    }
    __syncthreads();

    // ---- layer 2: [64x512] x [512x512]^T -> h2 (in place after sync) ----
    {
        f32x4 acc[4][4];
#pragma unroll
        for (int i = 0; i < 4; ++i)
#pragma unroll
            for (int j = 0; j < 4; ++j) acc[i][j] = (f32x4){0.f, 0.f, 0.f, 0.f};
        gemm4<NHID, LDBH>(ldsH, W2p + (size_t)s * NHID * NHID, lane, wtile, acc);
        __syncthreads();   // all h1 reads done before overwrite
        act_store<LDBH>(ldsH, b2 + s * NHID, lane, ncb, acc);
    }
    __syncthreads();

    // ---- layer 3: out[m] = dot(h2[m,:], W3[s]) + b3[s]; 8 thr/row ----
    {
        int m = tid >> 3;        // 0..63
        int q = tid & 7;         // 64-col eighth
        const us* W3s = W3b + (size_t)s * NHID;
        float sum = 0.f;
#pragma unroll
        for (int j = 0; j < 8; ++j) {
            int hh = q * 64 + j * 8;
            bf16x8 hv = *(const bf16x8*)(ldsH + m * LDBH + hh * 2);
            bf16x8 wv = *(const bf16x8*)(W3s + hh);
#pragma unroll
            for (int e = 0; e < 8; ++e) {
                union { unsigned u; float f; } ha, wa;
                ha.u = ((unsigned)(us)hv[e]) << 16;
                wa.u = ((unsigned)(us)wv[e]) << 16;
                sum += ha.f * wa.f;
            }
        }
        sum += __shfl_xor(sum, 1);
        sum += __shfl_xor(sum, 2);
        sum += __shfl_xor(sum, 4);
        if (q == 0 && m < cnt_t) out[list[base + m]] = sum + b3[s];
    }
}

extern "C" void kernel_launch(void* const* d_in, const int* in_sizes, int n_in,
                              void* d_out, int out_size, void* d_ws, size_t ws_size,
                              hipStream_t stream) {
    const float* x  = (const float*)d_in[0];
    const int*   z  = (const int*)d_in[1];
    const float* W1 = (const float*)d_in[2];
    const float* b1 = (const float*)d_in[3];
    const float* W2 = (const float*)d_in[4];
    const float* b2 = (const float*)d_in[5];
    const float* W3 = (const float*)d_in[6];
    const float* b3 = (const float*)d_in[7];
    float* out = (float*)d_out;

    char* ws = (char*)d_ws;
    int* cnt = (int*)ws;                                      // 16 B
    int* lists = (int*)(ws + 256);                            // 1 MB
    us* W1p = (us*)(ws + 256 + (size_t)4 * NATOMS * 4);       // 1 MB
    us* W2p = W1p + 4 * NHID * NIN;                           // 2 MB
    us* W3b = W2p + 4 * NHID * NHID;                          // 4 KB

    (void)hipMemsetAsync(cnt, 0, 16, stream);
    cvt_kernel<<<512, 256, 0, stream>>>(W1, W2, W3, W1p, W2p, W3b);
    compact_kernel<<<NATOMS / 1024, 1024, 0, stream>>>(z, cnt, lists, out);
    mlp_kernel<<<4096, 512, 0, stream>>>(x, cnt, lists, W1p, W2p, W3b, b1, b2, b3, out);
}